// Round 8
// baseline (248.571 us; speedup 1.0000x reference)
//
#include <hip/hip_runtime.h>
#include <hip/hip_bf16.h>
#include <stdint.h>

typedef unsigned short u16;
typedef __attribute__((ext_vector_type(8))) __bf16 bf16x8;
typedef __attribute__((ext_vector_type(4))) float f32x4;

__device__ __forceinline__ float bf2f(u16 u) {
  union { uint32_t u; float f; } v; v.u = ((uint32_t)u) << 16;
  return v.f;
}

// packed cvt: two fp32 -> one u32 holding (lo=a, hi=b) bf16
__device__ __forceinline__ uint32_t pk2(float a, float b) {
  union { __hip_bfloat162 h; uint32_t u; } x;
  x.h = __float22bfloat162_rn(make_float2(a, b));
  return x.u;
}

__device__ __forceinline__ void gl_lds16(const void* g, void* l) {
  __builtin_amdgcn_global_load_lds((const __attribute__((address_space(1))) void*)g,
                                   (__attribute__((address_space(3))) void*)l,
                                   16, 0, 0);
}

__device__ __forceinline__ f32x4 mfma16(bf16x8 a, bf16x8 b, f32x4 c) {
  return __builtin_amdgcn_mfma_f32_16x16x32_bf16(a, b, c, 0, 0, 0);
}

// raw workgroup barrier with compiler memory fence (no vmcnt/lgkm drain)
__device__ __forceinline__ void bar() {
  asm volatile("" ::: "memory");
  __builtin_amdgcn_s_barrier();
  asm volatile("" ::: "memory");
}

// ---------------- fused preprocessing ----------------
// z<4: transpose+cvt W_z[k][n] fp32 -> Wt[n][k] bf16 (grid (32,32) per z)
// z==4: x fp32 -> bf16 elementwise
__global__ void prep_kernel(const float* __restrict__ W0, const float* __restrict__ W1,
                            const float* __restrict__ W2, const float* __restrict__ W3,
                            u16* __restrict__ wout,
                            const float* __restrict__ xsrc, u16* __restrict__ xdst) {
  int z = blockIdx.z;
  if (z == 4) {
    int lin = blockIdx.y * 32 + blockIdx.x;   // 0..1023
    int tid = threadIdx.x;
#pragma unroll
    for (int p = 0; p < 4; ++p) {
      int i4 = (lin * 4 + p) * 256 + tid;     // float4 index, coalesced per pass
      float4 f = *(const float4*)(xsrc + (size_t)i4 * 4);
      uint2 o;
      o.x = pk2(f.x, f.y);
      o.y = pk2(f.z, f.w);
      *(uint2*)(xdst + (size_t)i4 * 4) = o;
    }
    return;
  }
  __shared__ float tile[64][65];
  const float* W = (z == 0) ? W0 : (z == 1) ? W1 : (z == 2) ? W2 : W3;
  u16* dst = wout + (size_t)z * 2048 * 2048;
  int k0 = blockIdx.y * 64, n0 = blockIdx.x * 64;
  int row4 = threadIdx.x >> 4;           // 0..15
  int col4 = (threadIdx.x & 15) * 4;     // 0..60
#pragma unroll
  for (int p = 0; p < 4; ++p) {
    int row = p * 16 + row4;
    float4 f = *(const float4*)(W + (size_t)(k0 + row) * 2048 + n0 + col4);
    tile[row][col4 + 0] = f.x;
    tile[row][col4 + 1] = f.y;
    tile[row][col4 + 2] = f.z;
    tile[row][col4 + 3] = f.w;
  }
  __syncthreads();
  int kc = threadIdx.x & 7;        // 8-wide k chunk
  int rbase = threadIdx.x >> 3;    // 0..31
#pragma unroll
  for (int p = 0; p < 2; ++p) {
    int n = rbase + p * 32;        // n-local row
    uint4 o;
    o.x = pk2(tile[kc * 8 + 0][n], tile[kc * 8 + 1][n]);
    o.y = pk2(tile[kc * 8 + 2][n], tile[kc * 8 + 3][n]);
    o.z = pk2(tile[kc * 8 + 4][n], tile[kc * 8 + 5][n]);
    o.w = pk2(tile[kc * 8 + 6][n], tile[kc * 8 + 7][n]);
    *(uint4*)(dst + (size_t)(n0 + n) * 2048 + k0 + kc * 8) = o;
  }
}

// ---------------- bf16 GEMM, m97-style (PROVEN): QKV projections ----------------
// 1D grid 768, XCD-aware B-resident swizzle. tn in [0,48): proj=tn>>4, h=tn&15
//   proj 0: Q[h][s][d] = (acc+bq)*(log2e/sqrt(128)); proj 1: K; proj 2: Vt[h][d][s]
__launch_bounds__(256, 2)
__global__ void gemm_bt(const u16* __restrict__ A, const u16* __restrict__ Bt,
                        const float* __restrict__ b0, const float* __restrict__ b1,
                        const float* __restrict__ b2,
                        u16* __restrict__ outQ, u16* __restrict__ outK,
                        u16* __restrict__ outVT) {
  extern __shared__ char smem[];
  u16* As = (u16*)smem;              // [128][64] bf16, 16B-chunk XOR swizzled
  u16* Bs = (u16*)(smem + 16384);
  const int K = 2048;
  const int tid = threadIdx.x;
  const int lane = tid & 63, wid = tid >> 6;
  const int c = lane & 15, q = lane >> 4;
  const int wm = wid >> 1, wn = wid & 1;
  const int bid = blockIdx.x;
  const int xcd = bid & 7, idx = bid >> 3;     // idx 0..95
  const int tn = xcd * 6 + idx % 6;
  const int tm = idx / 6;
  const size_t Abase = (size_t)tm * 128 * K;
  const size_t Bbase = (size_t)tn * 128 * K;

  f32x4 acc[4][4] = {};

  for (int kt = 0; kt < K / 64; ++kt) {
#pragma unroll
    for (int t = 0; t < 4; ++t) {
      int slot = wid * 256 + t * 64 + lane;
      int row = slot >> 3, cs = slot & 7;
      int cc = cs ^ (row & 7);
      const u16* ga = A + Abase + (size_t)row * K + kt * 64 + cc * 8;
      gl_lds16(ga, (char*)As + (size_t)(wid * 256 + t * 64) * 16);
      const u16* gb = Bt + Bbase + (size_t)row * K + kt * 64 + cc * 8;
      gl_lds16(gb, (char*)Bs + (size_t)(wid * 256 + t * 64) * 16);
    }
    __syncthreads();
#pragma unroll
    for (int kc = 0; kc < 2; ++kc) {
      bf16x8 af[4], bfr[4];
#pragma unroll
      for (int i = 0; i < 4; ++i) {
        int rowa = wm * 64 + i * 16 + c;
        int cha = ((kc << 2) | q) ^ (rowa & 7);
        af[i] = *(const bf16x8*)((const char*)As + rowa * 128 + cha * 16);
        int rowb = wn * 64 + i * 16 + c;
        int chb = ((kc << 2) | q) ^ (rowb & 7);
        bfr[i] = *(const bf16x8*)((const char*)Bs + rowb * 128 + chb * 16);
      }
#pragma unroll
      for (int i = 0; i < 4; ++i)
#pragma unroll
        for (int j = 0; j < 4; ++j)
          acc[i][j] = mfma16(af[i], bfr[j], acc[i][j]);
    }
    __syncthreads();
  }

  int proj = tn >> 4;
  int h = tn & 15;
  const float* bias = (proj == 0) ? b0 : (proj == 1) ? b1 : b2;
  if (proj < 2) {
    u16* out = (proj == 0) ? outQ : outK;
    // proj 0: (1/sqrt(128)) * log2(e)  — attn computes exp2(S) directly
    float scale = (proj == 0) ? 0.12751744751896235f : 1.0f;
#pragma unroll
    for (int i = 0; i < 4; ++i) {
      int s0 = tm * 128 + wm * 64 + i * 16 + q * 4;
#pragma unroll
      for (int j = 0; j < 4; ++j) {
        int d = wn * 64 + j * 16 + c;
        float bv = bias[h * 128 + d];
        uint32_t p01 = pk2((acc[i][j][0] + bv) * scale, (acc[i][j][1] + bv) * scale);
        uint32_t p23 = pk2((acc[i][j][2] + bv) * scale, (acc[i][j][3] + bv) * scale);
        u16* o = out + ((size_t)h * 2048 + s0) * 128 + d;
        o[0]   = (u16)p01;
        o[128] = (u16)(p01 >> 16);
        o[256] = (u16)p23;
        o[384] = (u16)(p23 >> 16);
      }
    }
  } else {
    // V: transpose via LDS -> Vt[h][d][s]
    u16* Cs = (u16*)smem;  // [128][136]
#pragma unroll
    for (int i = 0; i < 4; ++i) {
      int sl = wm * 64 + i * 16 + q * 4;
#pragma unroll
      for (int j = 0; j < 4; ++j) {
        int dl = wn * 64 + j * 16 + c;
        float bv = bias[h * 128 + dl];
        uint2 pk;
        pk.x = pk2(acc[i][j][0] + bv, acc[i][j][1] + bv);
        pk.y = pk2(acc[i][j][2] + bv, acc[i][j][3] + bv);
        *(uint2*)(Cs + dl * 136 + sl) = pk;
      }
    }
    __syncthreads();
#pragma unroll
    for (int rr = 0; rr < 8; ++rr) {
      int d = rr * 16 + (tid >> 4);
      int sc = (tid & 15) * 8;
      uint4 vv = *(const uint4*)(Cs + d * 136 + sc);
      *(uint4*)(outVT + ((size_t)(h * 128 + d)) * 2048 + tm * 128 + sc) = vv;
    }
  }
}

// ---------------- O-projection GEMM: 128x128 tiles, triple-buffered counted-vmcnt ----
// (round-5 winner, unchanged) Grid 256 = 1 block/CU, 3 LDS buffers, stage 2 ahead.
__launch_bounds__(256, 1)
__global__ void gemm_op(const u16* __restrict__ A, const u16* __restrict__ Bt,
                        const float* __restrict__ bias, float* __restrict__ out) {
  extern __shared__ char smem[];
  const int K = 2048, NT = 32;
  const int tid = threadIdx.x;
  const int lane = tid & 63, wid = tid >> 6;
  const int c = lane & 15, q = lane >> 4;
  const int wm = wid >> 1, wn = wid & 1;
  const int bid = blockIdx.x;
  const int xcd = bid & 7, idx = bid >> 3;     // idx 0..31
  const int tn = xcd * 2 + (idx & 1);
  const int tm = idx >> 1;
  const size_t Abase = (size_t)tm * 128 * K;
  const size_t Bbase = (size_t)tn * 128 * K;

  f32x4 acc[4][4] = {};

  auto STAGE = [&](int kt, int buf) {
    char* As = smem + buf * 32768;
    char* Bs = smem + buf * 32768 + 16384;
#pragma unroll
    for (int t = 0; t < 4; ++t) {
      int slot = wid * 256 + t * 64 + lane;
      int row = slot >> 3, cs = slot & 7;
      int cc = cs ^ (row & 7);
      gl_lds16(A + Abase + (size_t)row * K + kt * 64 + cc * 8, As + (size_t)slot * 16);
      gl_lds16(Bt + Bbase + (size_t)row * K + kt * 64 + cc * 8, Bs + (size_t)slot * 16);
    }
  };

  STAGE(0, 0);
  STAGE(1, 1);

  for (int kt = 0; kt < NT; ++kt) {
    const int buf = kt % 3;
    if (kt + 2 < NT) {
      STAGE(kt + 2, (kt + 2) % 3);
      asm volatile("s_waitcnt vmcnt(16)" ::: "memory");
    } else if (kt + 1 < NT) {
      asm volatile("s_waitcnt vmcnt(8)" ::: "memory");
    } else {
      asm volatile("s_waitcnt vmcnt(0)" ::: "memory");
    }
    __builtin_amdgcn_sched_barrier(0);
    bar();

    const char* As = smem + buf * 32768;
    const char* Bs = smem + buf * 32768 + 16384;
#pragma unroll
    for (int kc = 0; kc < 2; ++kc) {
      bf16x8 af[4], bfr[4];
#pragma unroll
      for (int i = 0; i < 4; ++i) {
        int rowa = wm * 64 + i * 16 + c;
        int cha = ((kc << 2) | q) ^ (rowa & 7);
        af[i] = *(const bf16x8*)(As + rowa * 128 + cha * 16);
        int rowb = wn * 64 + i * 16 + c;
        int chb = ((kc << 2) | q) ^ (rowb & 7);
        bfr[i] = *(const bf16x8*)(Bs + rowb * 128 + chb * 16);
      }
      __builtin_amdgcn_s_setprio(1);
#pragma unroll
      for (int i = 0; i < 4; ++i)
#pragma unroll
        for (int j = 0; j < 4; ++j)
          acc[i][j] = mfma16(af[i], bfr[j], acc[i][j]);
      __builtin_amdgcn_s_setprio(0);
    }
    bar();
  }

#pragma unroll
  for (int i = 0; i < 4; ++i) {
    int rowg = tm * 128 + wm * 64 + i * 16 + q * 4;
#pragma unroll
    for (int j = 0; j < 4; ++j) {
      int colg = tn * 128 + wn * 64 + j * 16 + c;
      float bv = bias[colg];
#pragma unroll
      for (int r = 0; r < 4; ++r)
        out[(size_t)(rowg + r) * 2048 + colg] = acc[i][j][r] + bv;
    }
  }
}

// ---------------- flash attention, causal, split-K(2), max-free softmax ----------------
// THIS ROUND: QBLK 128 -> 256 via 8 waves (512 thr), per-wave footprint UNCHANGED
// (32 q-rows/wave: qf[2][4], sacc[2][4], oacc[2][8]). Halves K/V->LDS staging
// traffic (139 -> 74 MB), which the round-6/7 flatness identified as attn's floor.
// Grid 256 (16 h x 8 qt x 2 splits) = 1 block/CU, all co-resident; 8 waves/CU same
// as before. LDS 96 KB: K dbuf 2x16K @0, V dbuf 2x16K @32K, P 8x4K @64K.
// Schedule per step (1 barrier, proven round 7): vmcnt(0) -> bar -> STAGE(t+1) ->
// QK -> mask/exp2 -> P(wave-private) -> PV. Split-K: split0 tiles [0, 2qt+2),
// split1 [2qt+2, 4qt+4). Mask gate kt >= 4*qt (per-lane exact check inside).
// Stores RAW partial O (bf16) + row-sum l; combine divides by (l0+l1).
__launch_bounds__(512, 1)
__global__ void attn_kernel(const u16* __restrict__ Qb, const u16* __restrict__ Kb,
                            const u16* __restrict__ Vt,
                            u16* __restrict__ Opb, float* __restrict__ lpb) {
  extern __shared__ char smem[];
  int b = blockIdx.x;
  const int split = b >> 7;                 // 0..1
  const int qt = (b >> 4) & 7;              // 0..7 (256-row q-tile)
  const int h = b & 15;
  u16* Op = Opb + (size_t)split * 4194304;
  float* lp = lpb + (size_t)split * 32768;
  const int ktBase = split ? (2 * qt + 2) : 0;
  const int ntiles = 2 * qt + 2;

  const int tid = threadIdx.x, lane = tid & 63, wid = tid >> 6;   // wid 0..7
  const int c = lane & 15, q = lane >> 4;

  bf16x8 qf[2][4];
#pragma unroll
  for (int i = 0; i < 2; ++i) {
    int s = qt * 256 + wid * 32 + i * 16 + c;
    const u16* qrow = Qb + ((size_t)h * 2048 + s) * 128;
#pragma unroll
    for (int kc = 0; kc < 4; ++kc)
      qf[i][kc] = *(const bf16x8*)(qrow + kc * 32 + q * 8);
  }

  f32x4 oacc[2][8] = {};
  float lst[2][4] = {};

  // K tile -> smem + buf*16K ([64 keys][128 dk] swizzled);
  // V tile -> smem + 32K + buf*16K ([128 d][64 s] swizzled). 512 thr x 2 passes each.
  auto STAGE = [&](int kt, int buf) {
    char* Kd = smem + buf * 16384;
    char* Vd = smem + 32768 + buf * 16384;
#pragma unroll
    for (int t = 0; t < 2; ++t) {
      int slot = t * 512 + tid;             // 0..1023 (16B slots)
      int rowk = slot >> 4, csk = slot & 15;
      int cck = csk ^ (rowk & 7);
      const u16* gk = Kb + ((size_t)h * 2048 + kt * 64 + rowk) * 128 + cck * 8;
      gl_lds16(gk, Kd + (size_t)slot * 16);
      int rowv = slot >> 3, csv = slot & 7;
      int ccv = csv ^ (rowv & 7);
      const u16* gv = Vt + ((size_t)(h * 128 + rowv)) * 2048 + kt * 64 + ccv * 8;
      gl_lds16(gv, Vd + (size_t)slot * 16);
    }
  };

  STAGE(ktBase, 0);
  int cur = 0;
  char* Pw = smem + 65536 + wid * 4096;     // dedicated per-wave P slab (8 x 4K)

  for (int tt = 0; tt < ntiles; ++tt) {
    const int kt = ktBase + tt;
    asm volatile("s_waitcnt vmcnt(0)" ::: "memory");
    __builtin_amdgcn_sched_barrier(0);
    bar();                                  // single per-step barrier
    if (tt + 1 < ntiles) STAGE(kt + 1, cur ^ 1);

    const char* Ksb = smem + cur * 16384;
    const char* Vsb = smem + 32768 + cur * 16384;

    f32x4 sacc[2][4] = {};
    __builtin_amdgcn_s_setprio(1);
#pragma unroll
    for (int kc = 0; kc < 4; ++kc) {
      bf16x8 bfr[4];
#pragma unroll
      for (int j = 0; j < 4; ++j) {
        int row = j * 16 + c;
        int ch = ((kc << 2) | q) ^ (row & 7);
        bfr[j] = *(const bf16x8*)(Ksb + row * 256 + ch * 16);
      }
#pragma unroll
      for (int i = 0; i < 2; ++i)
#pragma unroll
        for (int j = 0; j < 4; ++j)
          sacc[i][j] = mfma16(qf[i][kc], bfr[j], sacc[i][j]);
    }
    __builtin_amdgcn_s_setprio(0);

    if (kt >= 4 * qt) {                     // diagonal-crossing gate (per-lane exact below)
#pragma unroll
      for (int i = 0; i < 2; ++i)
#pragma unroll
        for (int j = 0; j < 4; ++j) {
          int key = kt * 64 + j * 16 + c;
#pragma unroll
          for (int r = 0; r < 4; ++r) {
            int qrow = qt * 256 + wid * 32 + i * 16 + q * 4 + r;
            if (key > qrow) sacc[i][j][r] = -1e30f;
          }
        }
    }

#pragma unroll
    for (int i = 0; i < 2; ++i)
#pragma unroll
      for (int j = 0; j < 4; ++j)
#pragma unroll
        for (int r = 0; r < 4; ++r) {
          float p = __builtin_amdgcn_exp2f(sacc[i][j][r]);   // log2e pre-folded into Q
          sacc[i][j][r] = p;
          lst[i][r] += p;
        }

#pragma unroll
    for (int i = 0; i < 2; ++i)
#pragma unroll
      for (int j = 0; j < 4; ++j) {
        uint32_t p01 = pk2(sacc[i][j][0], sacc[i][j][1]);
        uint32_t p23 = pk2(sacc[i][j][2], sacc[i][j][3]);
        int cb = (j << 1) | (c >> 3);
        int r0 = i * 16 + q * 4;
        int wb = (c & 7) << 1;
        *(u16*)(Pw + (r0 + 0) * 128 + ((cb ^ ((r0 + 0) & 7)) << 4) + wb) = (u16)p01;
        *(u16*)(Pw + (r0 + 1) * 128 + ((cb ^ ((r0 + 1) & 7)) << 4) + wb) = (u16)(p01 >> 16);
        *(u16*)(Pw + (r0 + 2) * 128 + ((cb ^ ((r0 + 2) & 7)) << 4) + wb) = (u16)p23;
        *(u16*)(Pw + (r0 + 3) * 128 + ((cb ^ ((r0 + 3) & 7)) << 4) + wb) = (u16)(p23 >> 16);
      }

    __builtin_amdgcn_s_setprio(1);
#pragma unroll
    for (int kc = 0; kc < 2; ++kc) {
      bf16x8 af[2], bv[8];
#pragma unroll
      for (int i = 0; i < 2; ++i) {
        int prow = i * 16 + c;
        af[i] = *(const bf16x8*)(Pw + prow * 128 + ((((kc << 2) | q) ^ (prow & 7)) << 4));
      }
#pragma unroll
      for (int jo = 0; jo < 8; ++jo) {
        int row = jo * 16 + c;
        int ch = ((kc << 2) | q) ^ (row & 7);
        bv[jo] = *(const bf16x8*)(Vsb + row * 128 + ch * 16);
      }
#pragma unroll
      for (int i = 0; i < 2; ++i)
#pragma unroll
        for (int jo = 0; jo < 8; ++jo)
          oacc[i][jo] = mfma16(bv[jo], af[i], oacc[i][jo]);
    }
    __builtin_amdgcn_s_setprio(0);
    cur ^= 1;
  }

#pragma unroll
  for (int i = 0; i < 2; ++i)
#pragma unroll
    for (int r = 0; r < 4; ++r) {
      float l = lst[i][r];
      l += __shfl_xor(l, 1);
      l += __shfl_xor(l, 2);
      l += __shfl_xor(l, 4);
      l += __shfl_xor(l, 8);
      if (c == 0)
        lp[(size_t)h * 2048 + qt * 256 + wid * 32 + i * 16 + q * 4 + r] = l;
    }
#pragma unroll
  for (int i = 0; i < 2; ++i) {
    int s = qt * 256 + wid * 32 + i * 16 + c;
#pragma unroll
    for (int jo = 0; jo < 8; ++jo) {
      uint2 o;
      o.x = pk2(oacc[i][jo][0], oacc[i][jo][1]);
      o.y = pk2(oacc[i][jo][2], oacc[i][jo][3]);
      *(uint2*)(Op + ((size_t)h * 2048 + s) * 128 + jo * 16 + q * 4) = o;
    }
  }
}

// ---------------- combine: AO = (O0+O1)/(l0+l1), bf16 out [s][h*128+d] ----------------
__global__ void attn_combine(const u16* __restrict__ Opb, const float* __restrict__ lpb,
                             u16* __restrict__ AO) {
  int g = blockIdx.x * 256 + threadIdx.x;
  int row = g >> 4;
  int dd = (g & 15) * 8;
  int h = row >> 11, s = row & 2047;
  float inv = 1.0f / (lpb[row] + lpb[row + 32768]);
  uint4 a = *(const uint4*)(Opb + (size_t)row * 128 + dd);
  uint4 bb = *(const uint4*)(Opb + 4194304 + (size_t)row * 128 + dd);
  const u16* pa = (const u16*)&a;
  const u16* pb = (const u16*)&bb;
  uint4 res;
  uint32_t* pr = (uint32_t*)&res;
#pragma unroll
  for (int t = 0; t < 4; ++t)
    pr[t] = pk2((bf2f(pa[2 * t]) + bf2f(pb[2 * t])) * inv,
                (bf2f(pa[2 * t + 1]) + bf2f(pb[2 * t + 1])) * inv);
  *(uint4*)(AO + (size_t)s * 2048 + h * 128 + dd) = res;
}

extern "C" void kernel_launch(void* const* d_in, const int* in_sizes, int n_in,
                              void* d_out, int out_size, void* d_ws, size_t ws_size,
                              hipStream_t stream) {
  const float* x  = (const float*)d_in[0];
  const float* Wq = (const float*)d_in[1];
  const float* bq = (const float*)d_in[2];
  const float* Wk = (const float*)d_in[3];
  const float* bk = (const float*)d_in[4];
  const float* Wv = (const float*)d_in[5];
  const float* bv = (const float*)d_in[6];
  const float* Wo = (const float*)d_in[7];
  const float* bo = (const float*)d_in[8];

  char* ws = (char*)d_ws;
  u16* xb = (u16*)(ws);                          // x bf16            0- 8 MB
  u16* wt = (u16*)(ws + (size_t)8  * 1048576);   // Wq/k/v/o^T bf16   8-40 MB
  u16* Qb = (u16*)(ws + (size_t)40 * 1048576);   // Q [h][s][d]      40-48 MB
  u16* Kb = (u16*)(ws + (size_t)48 * 1048576);   // K [h][s][d]      48-56 MB
  u16* Vt = (u16*)(ws + (size_t)56 * 1048576);   // V^T [h][d][s]    56-64 MB
  u16* AO = (u16*)(ws + (size_t)64 * 1048576);   // attn out [s][D]  64-72 MB
  u16* Opb = (u16*)(ws);
  float* lpb = (float*)d_out;

  static bool inited = false;
  if (!inited) {
    hipFuncSetAttribute((const void*)gemm_op,
                        hipFuncAttributeMaxDynamicSharedMemorySize, 98304);
    hipFuncSetAttribute((const void*)attn_kernel,
                        hipFuncAttributeMaxDynamicSharedMemorySize, 98304);
    inited = true;
  }

  prep_kernel<<<dim3(32, 32, 5), 256, 0, stream>>>(Wq, Wk, Wv, Wo, wt, x, xb);
  gemm_bt<<<768, 256, 34816, stream>>>(xb, wt, bq, bk, bv, Qb, Kb, Vt);
  attn_kernel<<<256, 512, 98304, stream>>>(Qb, Kb, Vt, Opb, lpb);
  attn_combine<<<2048, 256, 0, stream>>>(Opb, lpb, AO);
  gemm_op<<<256, 256, 98304, stream>>>(AO, wt + (size_t)3 * 2048 * 2048,
                                       bo, (float*)d_out);
}

// Round 10
// 239.965 us; speedup vs baseline: 1.0359x; 1.0359x over previous
//
#include <hip/hip_runtime.h>
#include <hip/hip_bf16.h>
#include <stdint.h>

typedef unsigned short u16;
typedef __attribute__((ext_vector_type(8))) __bf16 bf16x8;
typedef __attribute__((ext_vector_type(4))) float f32x4;

__device__ __forceinline__ float bf2f(u16 u) {
  union { uint32_t u; float f; } v; v.u = ((uint32_t)u) << 16;
  return v.f;
}

// packed cvt: two fp32 -> one u32 holding (lo=a, hi=b) bf16
__device__ __forceinline__ uint32_t pk2(float a, float b) {
  union { __hip_bfloat162 h; uint32_t u; } x;
  x.h = __float22bfloat162_rn(make_float2(a, b));
  return x.u;
}

__device__ __forceinline__ void gl_lds16(const void* g, void* l) {
  __builtin_amdgcn_global_load_lds((const __attribute__((address_space(1))) void*)g,
                                   (__attribute__((address_space(3))) void*)l,
                                   16, 0, 0);
}

__device__ __forceinline__ f32x4 mfma16(bf16x8 a, bf16x8 b, f32x4 c) {
  return __builtin_amdgcn_mfma_f32_16x16x32_bf16(a, b, c, 0, 0, 0);
}

// raw workgroup barrier with compiler memory fence (no vmcnt/lgkm drain)
__device__ __forceinline__ void bar() {
  asm volatile("" ::: "memory");
  __builtin_amdgcn_s_barrier();
  asm volatile("" ::: "memory");
}

// ---------------- fused preprocessing ----------------
// z<4: transpose+cvt W_z[k][n] fp32 -> Wt[n][k] bf16 (grid (32,32) per z)
// z==4: x fp32 -> bf16 elementwise
__global__ void prep_kernel(const float* __restrict__ W0, const float* __restrict__ W1,
                            const float* __restrict__ W2, const float* __restrict__ W3,
                            u16* __restrict__ wout,
                            const float* __restrict__ xsrc, u16* __restrict__ xdst) {
  int z = blockIdx.z;
  if (z == 4) {
    int lin = blockIdx.y * 32 + blockIdx.x;   // 0..1023
    int tid = threadIdx.x;
#pragma unroll
    for (int p = 0; p < 4; ++p) {
      int i4 = (lin * 4 + p) * 256 + tid;     // float4 index, coalesced per pass
      float4 f = *(const float4*)(xsrc + (size_t)i4 * 4);
      uint2 o;
      o.x = pk2(f.x, f.y);
      o.y = pk2(f.z, f.w);
      *(uint2*)(xdst + (size_t)i4 * 4) = o;
    }
    return;
  }
  __shared__ float tile[64][65];
  const float* W = (z == 0) ? W0 : (z == 1) ? W1 : (z == 2) ? W2 : W3;
  u16* dst = wout + (size_t)z * 2048 * 2048;
  int k0 = blockIdx.y * 64, n0 = blockIdx.x * 64;
  int row4 = threadIdx.x >> 4;           // 0..15
  int col4 = (threadIdx.x & 15) * 4;     // 0..60
#pragma unroll
  for (int p = 0; p < 4; ++p) {
    int row = p * 16 + row4;
    float4 f = *(const float4*)(W + (size_t)(k0 + row) * 2048 + n0 + col4);
    tile[row][col4 + 0] = f.x;
    tile[row][col4 + 1] = f.y;
    tile[row][col4 + 2] = f.z;
    tile[row][col4 + 3] = f.w;
  }
  __syncthreads();
  int kc = threadIdx.x & 7;        // 8-wide k chunk
  int rbase = threadIdx.x >> 3;    // 0..31
#pragma unroll
  for (int p = 0; p < 2; ++p) {
    int n = rbase + p * 32;        // n-local row
    uint4 o;
    o.x = pk2(tile[kc * 8 + 0][n], tile[kc * 8 + 1][n]);
    o.y = pk2(tile[kc * 8 + 2][n], tile[kc * 8 + 3][n]);
    o.z = pk2(tile[kc * 8 + 4][n], tile[kc * 8 + 5][n]);
    o.w = pk2(tile[kc * 8 + 6][n], tile[kc * 8 + 7][n]);
    *(uint4*)(dst + (size_t)(n0 + n) * 2048 + k0 + kc * 8) = o;
  }
}

// ---------------- bf16 GEMM, m97-style (PROVEN): QKV projections ----------------
// 1D grid 768, XCD-aware B-resident swizzle. tn in [0,48): proj=tn>>4, h=tn&15
//   proj 0: Q[h][s][d] = (acc+bq)*(log2e/sqrt(128)); proj 1: K; proj 2: Vt[h][d][s]
__launch_bounds__(256, 2)
__global__ void gemm_bt(const u16* __restrict__ A, const u16* __restrict__ Bt,
                        const float* __restrict__ b0, const float* __restrict__ b1,
                        const float* __restrict__ b2,
                        u16* __restrict__ outQ, u16* __restrict__ outK,
                        u16* __restrict__ outVT) {
  extern __shared__ char smem[];
  u16* As = (u16*)smem;              // [128][64] bf16, 16B-chunk XOR swizzled
  u16* Bs = (u16*)(smem + 16384);
  const int K = 2048;
  const int tid = threadIdx.x;
  const int lane = tid & 63, wid = tid >> 6;
  const int c = lane & 15, q = lane >> 4;
  const int wm = wid >> 1, wn = wid & 1;
  const int bid = blockIdx.x;
  const int xcd = bid & 7, idx = bid >> 3;     // idx 0..95
  const int tn = xcd * 6 + idx % 6;
  const int tm = idx / 6;
  const size_t Abase = (size_t)tm * 128 * K;
  const size_t Bbase = (size_t)tn * 128 * K;

  f32x4 acc[4][4] = {};

  for (int kt = 0; kt < K / 64; ++kt) {
#pragma unroll
    for (int t = 0; t < 4; ++t) {
      int slot = wid * 256 + t * 64 + lane;
      int row = slot >> 3, cs = slot & 7;
      int cc = cs ^ (row & 7);
      const u16* ga = A + Abase + (size_t)row * K + kt * 64 + cc * 8;
      gl_lds16(ga, (char*)As + (size_t)(wid * 256 + t * 64) * 16);
      const u16* gb = Bt + Bbase + (size_t)row * K + kt * 64 + cc * 8;
      gl_lds16(gb, (char*)Bs + (size_t)(wid * 256 + t * 64) * 16);
    }
    __syncthreads();
#pragma unroll
    for (int kc = 0; kc < 2; ++kc) {
      bf16x8 af[4], bfr[4];
#pragma unroll
      for (int i = 0; i < 4; ++i) {
        int rowa = wm * 64 + i * 16 + c;
        int cha = ((kc << 2) | q) ^ (rowa & 7);
        af[i] = *(const bf16x8*)((const char*)As + rowa * 128 + cha * 16);
        int rowb = wn * 64 + i * 16 + c;
        int chb = ((kc << 2) | q) ^ (rowb & 7);
        bfr[i] = *(const bf16x8*)((const char*)Bs + rowb * 128 + chb * 16);
      }
#pragma unroll
      for (int i = 0; i < 4; ++i)
#pragma unroll
        for (int j = 0; j < 4; ++j)
          acc[i][j] = mfma16(af[i], bfr[j], acc[i][j]);
    }
    __syncthreads();
  }

  int proj = tn >> 4;
  int h = tn & 15;
  const float* bias = (proj == 0) ? b0 : (proj == 1) ? b1 : b2;
  if (proj < 2) {
    u16* out = (proj == 0) ? outQ : outK;
    // proj 0: (1/sqrt(128)) * log2(e)  — attn computes exp2(S) directly
    float scale = (proj == 0) ? 0.12751744751896235f : 1.0f;
#pragma unroll
    for (int i = 0; i < 4; ++i) {
      int s0 = tm * 128 + wm * 64 + i * 16 + q * 4;
#pragma unroll
      for (int j = 0; j < 4; ++j) {
        int d = wn * 64 + j * 16 + c;
        float bv = bias[h * 128 + d];
        uint32_t p01 = pk2((acc[i][j][0] + bv) * scale, (acc[i][j][1] + bv) * scale);
        uint32_t p23 = pk2((acc[i][j][2] + bv) * scale, (acc[i][j][3] + bv) * scale);
        u16* o = out + ((size_t)h * 2048 + s0) * 128 + d;
        o[0]   = (u16)p01;
        o[128] = (u16)(p01 >> 16);
        o[256] = (u16)p23;
        o[384] = (u16)(p23 >> 16);
      }
    }
  } else {
    // V: transpose via LDS -> Vt[h][d][s]
    u16* Cs = (u16*)smem;  // [128][136]
#pragma unroll
    for (int i = 0; i < 4; ++i) {
      int sl = wm * 64 + i * 16 + q * 4;
#pragma unroll
      for (int j = 0; j < 4; ++j) {
        int dl = wn * 64 + j * 16 + c;
        float bv = bias[h * 128 + dl];
        uint2 pk;
        pk.x = pk2(acc[i][j][0] + bv, acc[i][j][1] + bv);
        pk.y = pk2(acc[i][j][2] + bv, acc[i][j][3] + bv);
        *(uint2*)(Cs + dl * 136 + sl) = pk;
      }
    }
    __syncthreads();
#pragma unroll
    for (int rr = 0; rr < 8; ++rr) {
      int d = rr * 16 + (tid >> 4);
      int sc = (tid & 15) * 8;
      uint4 vv = *(const uint4*)(Cs + d * 136 + sc);
      *(uint4*)(outVT + ((size_t)(h * 128 + d)) * 2048 + tm * 128 + sc) = vv;
    }
  }
}

// ---------------- O-projection GEMM: 128x128 tiles, triple-buffered counted-vmcnt ----
// (round-5 winner, unchanged) Grid 256 = 1 block/CU, 3 LDS buffers, stage 2 ahead.
__launch_bounds__(256, 1)
__global__ void gemm_op(const u16* __restrict__ A, const u16* __restrict__ Bt,
                        const float* __restrict__ bias, float* __restrict__ out) {
  extern __shared__ char smem[];
  const int K = 2048, NT = 32;
  const int tid = threadIdx.x;
  const int lane = tid & 63, wid = tid >> 6;
  const int c = lane & 15, q = lane >> 4;
  const int wm = wid >> 1, wn = wid & 1;
  const int bid = blockIdx.x;
  const int xcd = bid & 7, idx = bid >> 3;     // idx 0..31
  const int tn = xcd * 2 + (idx & 1);
  const int tm = idx >> 1;
  const size_t Abase = (size_t)tm * 128 * K;
  const size_t Bbase = (size_t)tn * 128 * K;

  f32x4 acc[4][4] = {};

  auto STAGE = [&](int kt, int buf) {
    char* As = smem + buf * 32768;
    char* Bs = smem + buf * 32768 + 16384;
#pragma unroll
    for (int t = 0; t < 4; ++t) {
      int slot = wid * 256 + t * 64 + lane;
      int row = slot >> 3, cs = slot & 7;
      int cc = cs ^ (row & 7);
      gl_lds16(A + Abase + (size_t)row * K + kt * 64 + cc * 8, As + (size_t)slot * 16);
      gl_lds16(Bt + Bbase + (size_t)row * K + kt * 64 + cc * 8, Bs + (size_t)slot * 16);
    }
  };

  STAGE(0, 0);
  STAGE(1, 1);

  for (int kt = 0; kt < NT; ++kt) {
    const int buf = kt % 3;
    if (kt + 2 < NT) {
      STAGE(kt + 2, (kt + 2) % 3);
      asm volatile("s_waitcnt vmcnt(16)" ::: "memory");
    } else if (kt + 1 < NT) {
      asm volatile("s_waitcnt vmcnt(8)" ::: "memory");
    } else {
      asm volatile("s_waitcnt vmcnt(0)" ::: "memory");
    }
    __builtin_amdgcn_sched_barrier(0);
    bar();

    const char* As = smem + buf * 32768;
    const char* Bs = smem + buf * 32768 + 16384;
#pragma unroll
    for (int kc = 0; kc < 2; ++kc) {
      bf16x8 af[4], bfr[4];
#pragma unroll
      for (int i = 0; i < 4; ++i) {
        int rowa = wm * 64 + i * 16 + c;
        int cha = ((kc << 2) | q) ^ (rowa & 7);
        af[i] = *(const bf16x8*)(As + rowa * 128 + cha * 16);
        int rowb = wn * 64 + i * 16 + c;
        int chb = ((kc << 2) | q) ^ (rowb & 7);
        bfr[i] = *(const bf16x8*)(Bs + rowb * 128 + chb * 16);
      }
      __builtin_amdgcn_s_setprio(1);
#pragma unroll
      for (int i = 0; i < 4; ++i)
#pragma unroll
        for (int j = 0; j < 4; ++j)
          acc[i][j] = mfma16(af[i], bfr[j], acc[i][j]);
      __builtin_amdgcn_s_setprio(0);
    }
    bar();
  }

#pragma unroll
  for (int i = 0; i < 4; ++i) {
    int rowg = tm * 128 + wm * 64 + i * 16 + q * 4;
#pragma unroll
    for (int j = 0; j < 4; ++j) {
      int colg = tn * 128 + wn * 64 + j * 16 + c;
      float bv = bias[colg];
#pragma unroll
      for (int r = 0; r < 4; ++r)
        out[(size_t)(rowg + r) * 2048 + colg] = acc[i][j][r] + bv;
    }
  }
}

// ---------------- flash attention, causal, split-K(2), max-free softmax ----------------
// ROUND-7 CONFIG (best measured): QBLK=128, grid 512, 2 blocks/CU with BALANCED
// PAIRING by construction — block c (ntiles=qt+1) and block c+256 (ntiles=16-qt)
// co-reside per CU and sum to 17 tile-steps on every CU.
// One barrier per step; dedicated per-wave P slab (LDS 80 KB = K dbuf 32K + V dbuf
// 32K + P 16K). Per step: vmcnt(0) -> bar -> STAGE(t+1, parity^1) -> QK ->
// mask/exp2 -> P write (wave-private) -> PV.
// Race ledger: tile t's K/V certified by [wait->bar] at step t entry; STAGE(t+2)
// overwrites parity-t buffers only after bar(t+1), which waves pass only after
// finishing QK(t)/PV(t) reads. P write->read same-wave (compiler lgkmcnt).
// Q pre-scaled by log2e/sqrt(128) -> softmax is exp2(S) directly.
// Stores RAW partial O (bf16) + row-sum l; combine divides by (l0+l1).
__launch_bounds__(256, 2)
__global__ void attn_kernel(const u16* __restrict__ Qb, const u16* __restrict__ Kb,
                            const u16* __restrict__ Vt,
                            u16* __restrict__ Opb, float* __restrict__ lpb) {
  extern __shared__ char smem[];
  int b = blockIdx.x;
  int split, qt, h;
  if (b < 256) { split = 0; qt = b >> 4; h = b & 15; }
  else { split = 1; int idx = b - 256; qt = 15 - (idx >> 4); h = idx & 15; }
  u16* Op = Opb + (size_t)split * 4194304;
  float* lp = lpb + (size_t)split * 32768;
  const int ktBase = split ? (qt + 1) : 0;
  const int ntiles = qt + 1;

  const int tid = threadIdx.x, lane = tid & 63, wid = tid >> 6;
  const int c = lane & 15, q = lane >> 4;

  bf16x8 qf[2][4];
#pragma unroll
  for (int i = 0; i < 2; ++i) {
    int s = qt * 128 + wid * 32 + i * 16 + c;
    const u16* qrow = Qb + ((size_t)h * 2048 + s) * 128;
#pragma unroll
    for (int kc = 0; kc < 4; ++kc)
      qf[i][kc] = *(const bf16x8*)(qrow + kc * 32 + q * 8);
  }

  f32x4 oacc[2][8] = {};
  float lst[2][4] = {};

  // K tile -> smem + buf*16K ; V tile -> smem + 32K + buf*16K
  auto STAGE = [&](int kt, int buf) {
    char* Kd = smem + buf * 16384;
    char* Vd = smem + 32768 + buf * 16384;
#pragma unroll
    for (int t = 0; t < 4; ++t) {
      int slot = (wid * 4 + t) * 64 + lane;
      int rowk = slot >> 4, csk = slot & 15;
      int cck = csk ^ (rowk & 7);
      const u16* gk = Kb + ((size_t)h * 2048 + kt * 64 + rowk) * 128 + cck * 8;
      gl_lds16(gk, Kd + (size_t)((wid * 4 + t) * 64) * 16);
      int rowv = slot >> 3, csv = slot & 7;
      int ccv = csv ^ (rowv & 7);
      const u16* gv = Vt + ((size_t)(h * 128 + rowv)) * 2048 + kt * 64 + ccv * 8;
      gl_lds16(gv, Vd + (size_t)((wid * 4 + t) * 64) * 16);
    }
  };

  STAGE(ktBase, 0);
  int cur = 0;
  char* Pw = smem + 65536 + wid * 4096;   // dedicated per-wave P slab

  for (int tt = 0; tt < ntiles; ++tt) {
    const int kt = ktBase + tt;
    asm volatile("s_waitcnt vmcnt(0)" ::: "memory");
    __builtin_amdgcn_sched_barrier(0);
    bar();                                     // single per-step barrier
    if (tt + 1 < ntiles) STAGE(kt + 1, cur ^ 1);

    const char* Ksb = smem + cur * 16384;
    const char* Vsb = smem + 32768 + cur * 16384;

    f32x4 sacc[2][4] = {};
    __builtin_amdgcn_s_setprio(1);
#pragma unroll
    for (int kc = 0; kc < 4; ++kc) {
      bf16x8 bfr[4];
#pragma unroll
      for (int j = 0; j < 4; ++j) {
        int row = j * 16 + c;
        int ch = ((kc << 2) | q) ^ (row & 7);
        bfr[j] = *(const bf16x8*)(Ksb + row * 256 + ch * 16);
      }
#pragma unroll
      for (int i = 0; i < 2; ++i)
#pragma unroll
        for (int j = 0; j < 4; ++j)
          sacc[i][j] = mfma16(qf[i][kc], bfr[j], sacc[i][j]);
    }
    __builtin_amdgcn_s_setprio(0);

    if (kt >= 2 * qt) {
#pragma unroll
      for (int i = 0; i < 2; ++i)
#pragma unroll
        for (int j = 0; j < 4; ++j) {
          int key = kt * 64 + j * 16 + c;
#pragma unroll
          for (int r = 0; r < 4; ++r) {
            int qrow = qt * 128 + wid * 32 + i * 16 + q * 4 + r;
            if (key > qrow) sacc[i][j][r] = -1e30f;
          }
        }
    }

#pragma unroll
    for (int i = 0; i < 2; ++i)
#pragma unroll
      for (int j = 0; j < 4; ++j)
#pragma unroll
        for (int r = 0; r < 4; ++r) {
          float p = __builtin_amdgcn_exp2f(sacc[i][j][r]);   // log2e pre-folded into Q
          sacc[i][j][r] = p;
          lst[i][r] += p;
        }

#pragma unroll
    for (int i = 0; i < 2; ++i)
#pragma unroll
      for (int j = 0; j < 4; ++j) {
        uint32_t p01 = pk2(sacc[i][j][0], sacc[i][j][1]);
        uint32_t p23 = pk2(sacc[i][j][2], sacc[i][j][3]);
        int cb = (j << 1) | (c >> 3);
        int r0 = i * 16 + q * 4;
        int wb = (c & 7) << 1;
        *(u16*)(Pw + (r0 + 0) * 128 + ((cb ^ ((r0 + 0) & 7)) << 4) + wb) = (u16)p01;
        *(u16*)(Pw + (r0 + 1) * 128 + ((cb ^ ((r0 + 1) & 7)) << 4) + wb) = (u16)(p01 >> 16);
        *(u16*)(Pw + (r0 + 2) * 128 + ((cb ^ ((r0 + 2) & 7)) << 4) + wb) = (u16)p23;
        *(u16*)(Pw + (r0 + 3) * 128 + ((cb ^ ((r0 + 3) & 7)) << 4) + wb) = (u16)(p23 >> 16);
      }

    __builtin_amdgcn_s_setprio(1);
#pragma unroll
    for (int kc = 0; kc < 2; ++kc) {
      bf16x8 af[2], bv[8];
#pragma unroll
      for (int i = 0; i < 2; ++i) {
        int prow = i * 16 + c;
        af[i] = *(const bf16x8*)(Pw + prow * 128 + ((((kc << 2) | q) ^ (prow & 7)) << 4));
      }
#pragma unroll
      for (int jo = 0; jo < 8; ++jo) {
        int row = jo * 16 + c;
        int ch = ((kc << 2) | q) ^ (row & 7);
        bv[jo] = *(const bf16x8*)(Vsb + row * 128 + ch * 16);
      }
#pragma unroll
      for (int i = 0; i < 2; ++i)
#pragma unroll
        for (int jo = 0; jo < 8; ++jo)
          oacc[i][jo] = mfma16(bv[jo], af[i], oacc[i][jo]);
    }
    __builtin_amdgcn_s_setprio(0);
    cur ^= 1;
  }

#pragma unroll
  for (int i = 0; i < 2; ++i)
#pragma unroll
    for (int r = 0; r < 4; ++r) {
      float l = lst[i][r];
      l += __shfl_xor(l, 1);
      l += __shfl_xor(l, 2);
      l += __shfl_xor(l, 4);
      l += __shfl_xor(l, 8);
      if (c == 0)
        lp[(size_t)h * 2048 + qt * 128 + wid * 32 + i * 16 + q * 4 + r] = l;
    }
#pragma unroll
  for (int i = 0; i < 2; ++i) {
    int s = qt * 128 + wid * 32 + i * 16 + c;
#pragma unroll
    for (int jo = 0; jo < 8; ++jo) {
      uint2 o;
      o.x = pk2(oacc[i][jo][0], oacc[i][jo][1]);
      o.y = pk2(oacc[i][jo][2], oacc[i][jo][3]);
      *(uint2*)(Op + ((size_t)h * 2048 + s) * 128 + jo * 16 + q * 4) = o;
    }
  }
}

// ---------------- combine: AO = (O0+O1)/(l0+l1), bf16 out [s][h*128+d] ----------------
__global__ void attn_combine(const u16* __restrict__ Opb, const float* __restrict__ lpb,
                             u16* __restrict__ AO) {
  int g = blockIdx.x * 256 + threadIdx.x;
  int row = g >> 4;
  int dd = (g & 15) * 8;
  int h = row >> 11, s = row & 2047;
  float inv = 1.0f / (lpb[row] + lpb[row + 32768]);
  uint4 a = *(const uint4*)(Opb + (size_t)row * 128 + dd);
  uint4 bb = *(const uint4*)(Opb + 4194304 + (size_t)row * 128 + dd);
  const u16* pa = (const u16*)&a;
  const u16* pb = (const u16*)&bb;
  uint4 res;
  uint32_t* pr = (uint32_t*)&res;
#pragma unroll
  for (int t = 0; t < 4; ++t)
    pr[t] = pk2((bf2f(pa[2 * t]) + bf2f(pb[2 * t])) * inv,
                (bf2f(pa[2 * t + 1]) + bf2f(pb[2 * t + 1])) * inv);
  *(uint4*)(AO + (size_t)s * 2048 + h * 128 + dd) = res;
}

extern "C" void kernel_launch(void* const* d_in, const int* in_sizes, int n_in,
                              void* d_out, int out_size, void* d_ws, size_t ws_size,
                              hipStream_t stream) {
  const float* x  = (const float*)d_in[0];
  const float* Wq = (const float*)d_in[1];
  const float* bq = (const float*)d_in[2];
  const float* Wk = (const float*)d_in[3];
  const float* bk = (const float*)d_in[4];
  const float* Wv = (const float*)d_in[5];
  const float* bv = (const float*)d_in[6];
  const float* Wo = (const float*)d_in[7];
  const float* bo = (const float*)d_in[8];

  char* ws = (char*)d_ws;
  u16* xb = (u16*)(ws);                          // x bf16            0- 8 MB
  u16* wt = (u16*)(ws + (size_t)8  * 1048576);   // Wq/k/v/o^T bf16   8-40 MB
  u16* Qb = (u16*)(ws + (size_t)40 * 1048576);   // Q [h][s][d]      40-48 MB
  u16* Kb = (u16*)(ws + (size_t)48 * 1048576);   // K [h][s][d]      48-56 MB
  u16* Vt = (u16*)(ws + (size_t)56 * 1048576);   // V^T [h][d][s]    56-64 MB
  u16* AO = (u16*)(ws + (size_t)64 * 1048576);   // attn out [s][D]  64-72 MB
  u16* Opb = (u16*)(ws);
  float* lpb = (float*)d_out;

  static bool inited = false;
  if (!inited) {
    hipFuncSetAttribute((const void*)gemm_op,
                        hipFuncAttributeMaxDynamicSharedMemorySize, 98304);
    hipFuncSetAttribute((const void*)attn_kernel,
                        hipFuncAttributeMaxDynamicSharedMemorySize, 81920);
    inited = true;
  }

  prep_kernel<<<dim3(32, 32, 5), 256, 0, stream>>>(Wq, Wk, Wv, Wo, wt, x, xb);
  gemm_bt<<<768, 256, 34816, stream>>>(xb, wt, bq, bk, bv, Qb, Kb, Vt);
  attn_kernel<<<512, 256, 81920, stream>>>(Qb, Kb, Vt, Opb, lpb);
  attn_combine<<<2048, 256, 0, stream>>>(Opb, lpb, AO);
  gemm_op<<<256, 256, 98304, stream>>>(AO, wt + (size_t)3 * 2048 * 2048,
                                       bo, (float*)d_out);
}